// Round 2
// baseline (1767.337 us; speedup 1.0000x reference)
//
#include <hip/hip_runtime.h>
#include <math.h>

typedef unsigned short u16;
typedef __attribute__((ext_vector_type(8))) unsigned short ushort8;
typedef __attribute__((ext_vector_type(8))) short short8;
typedef __attribute__((ext_vector_type(4))) float f32x4;

__device__ __forceinline__ float b2f(u16 v) {
    unsigned u = ((unsigned)v) << 16; float f; __builtin_memcpy(&f, &u, 4); return f;
}
__device__ __forceinline__ u16 f2b(float f) {
    unsigned u; __builtin_memcpy(&u, &f, 4);
    u = (u + 0x7fffu + ((u >> 16) & 1u)) >> 16;   // RNE
    return (u16)u;
}
// flag-branched raw-input load (flag: 1 = fp32 inputs, 0 = bf16 inputs)
__device__ __forceinline__ float ldin(const void* p, int i, int flag) {
    return flag ? ((const float*)p)[i] : b2f(((const u16*)p)[i]);
}
__device__ __forceinline__ void split2(float x, u16& h, u16& l) {
    h = f2b(x);
    l = f2b(x - b2f(h));
}

// ---------------------------------------------------------------------------
// dtype detector: fp32 N(0,1) words have exponent field in [77,157];
// bf16 pairs viewed as fp32 essentially never do. flag=1 -> fp32.
// ---------------------------------------------------------------------------
__global__ void detect_kernel(const unsigned* __restrict__ xw, int* __restrict__ flag) {
    __shared__ int red[4];
    int tid = threadIdx.x, lane = tid & 63, wid = tid >> 6;
    int cnt = 0;
    for (int i = 0; i < 16; ++i) {
        unsigned w = xw[tid * 16 + i];
        unsigned e = (w >> 23) & 0xFF;
        if (e >= 77u && e <= 157u) ++cnt;
    }
    for (int o = 32; o; o >>= 1) cnt += __shfl_down(cnt, o, 64);
    if (lane == 0) red[wid] = cnt;
    __syncthreads();
    if (tid == 0) flag[0] = (red[0] + red[1] + red[2] + red[3] >= 2048) ? 1 : 0;
}

// ---------------------------------------------------------------------------
// Spectral norm, one power iteration, fp32. inv_sigma[b] = 1/sigma.
// ---------------------------------------------------------------------------
__global__ void sigma_kernel(const void* __restrict__ w1, const void* __restrict__ u1,
                             const void* __restrict__ w2, const void* __restrict__ u2,
                             const void* __restrict__ wsb, const void* __restrict__ us,
                             const int* __restrict__ flagp, float* __restrict__ inv_sigma) {
    __shared__ float u_sh[512];
    __shared__ float t_sh[2304];
    __shared__ float red[4];
    __shared__ float bcast;
    int b = blockIdx.x;
    const void* W; const void* U; int h, m;
    if (b == 0)      { W = w1;  U = u1; h = 256; m = 2304; }
    else if (b == 1) { W = w2;  U = u2; h = 512; m = 2304; }
    else             { W = wsb; U = us; h = 512; m = 256;  }
    int tid = threadIdx.x, lane = tid & 63, wid = tid >> 6;
    int flag = flagp[0];

    for (int i = tid; i < h; i += 256) u_sh[i] = ldin(U, i, flag);
    __syncthreads();

    float nt = 0.f;
    for (int j = tid; j < m; j += 256) {
        float acc = 0.f;
        for (int i = 0; i < h; ++i) acc += ldin(W, i * m + j, flag) * u_sh[i];
        t_sh[j] = acc;
        nt += acc * acc;
    }
    for (int o = 32; o; o >>= 1) nt += __shfl_down(nt, o, 64);
    if (lane == 0) red[wid] = nt;
    __syncthreads();
    if (tid == 0) bcast = 1.f / (sqrtf(red[0] + red[1] + red[2] + red[3]) + 1e-12f);
    __syncthreads();
    float sc = bcast;
    for (int j = tid; j < m; j += 256) t_sh[j] *= sc;
    __syncthreads();

    float ns = 0.f;
    for (int i = tid; i < h; i += 256) {
        float acc = 0.f;
        for (int j = 0; j < m; ++j) acc += ldin(W, i * m + j, flag) * t_sh[j];
        ns += acc * acc;
    }
    for (int o = 32; o; o >>= 1) ns += __shfl_down(ns, o, 64);
    if (lane == 0) red[wid] = ns;
    __syncthreads();
    if (tid == 0) {
        float s2 = red[0] + red[1] + red[2] + red[3];
        float s  = sqrtf(s2);
        inv_sigma[b] = (s + 1e-12f) / s2;
    }
}

// ---------------------------------------------------------------------------
// Weight prep: scale by 1/sigma, transpose to [kyx][co][ci], split to hi/lo
// bf16 planes. Also canonicalizes biases to fp32 (tail indices).
// ---------------------------------------------------------------------------
__global__ void wprep_kernel(const void* __restrict__ w1b, const void* __restrict__ w2b,
                             const void* __restrict__ wsb,
                             const void* __restrict__ b1,  const void* __restrict__ b2,
                             const float* __restrict__ inv_sigma, const int* __restrict__ flagp,
                             u16* __restrict__ w1h, u16* __restrict__ w1l,
                             u16* __restrict__ w2h, u16* __restrict__ w2l,
                             u16* __restrict__ wsh, u16* __restrict__ wsl,
                             float* __restrict__ b1f, float* __restrict__ b2f_) {
    int idx = blockIdx.x * 256 + threadIdx.x;
    int flag = flagp[0];
    float s0 = inv_sigma[0], s1 = inv_sigma[1], s2 = inv_sigma[2];
    if (idx < 589824) {                       // 9*256*256
        int kyx = idx / 65536; int rem = idx - kyx * 65536;
        int co = rem >> 8, ci = rem & 255;
        float w = ldin(w1b, ((co << 8) + ci) * 9 + kyx, flag) * s0;
        split2(w, w1h[idx], w1l[idx]);
    } else if (idx < 589824 + 1179648) {      // 9*512*256
        int i2 = idx - 589824;
        int kyx = i2 / 131072; int rem = i2 - kyx * 131072;
        int co = rem >> 8, ci = rem & 255;
        float w = ldin(w2b, ((co << 8) + ci) * 9 + kyx, flag) * s1;
        split2(w, w2h[i2], w2l[i2]);
    } else if (idx < 1900544) {               // 512*256
        int i3 = idx - 1769472;
        float w = ldin(wsb, i3, flag) * s2;
        split2(w, wsh[i3], wsl[i3]);
    } else if (idx < 1900544 + 256) {
        b1f[idx - 1900544] = ldin(b1, idx - 1900544, flag);
    } else if (idx < 1900544 + 768) {
        b2f_[idx - 1900800] = ldin(b2, idx - 1900800, flag);
    }
}

// ---------------------------------------------------------------------------
// x NCHW -> xt fp32 NHWC for one 8-image chunk: xt[((nl*64+y)*64+x)*256+ci]
// ---------------------------------------------------------------------------
__global__ void transpose_kernel(const void* __restrict__ x, float* __restrict__ xt,
                                 const int* __restrict__ flagp, int n0) {
    __shared__ float tile[32][65];
    int flag = flagp[0];
    int ny  = blockIdx.x;                    // nl*64 + y, nl in [0,8)
    int ci0 = blockIdx.y * 32;
    int nl = ny >> 6, y = ny & 63;
    int t = threadIdx.x;
    int ci_l = t >> 3, x8 = (t & 7) * 8;
    int base = ((n0 + nl) * 256 + ci0 + ci_l) * 4096 + y * 64 + x8;
#pragma unroll
    for (int k = 0; k < 8; ++k) tile[ci_l][x8 + k] = ldin(x, base + k, flag);
    __syncthreads();
    int x_l = t >> 2, oc = (t & 3) * 8;
    float* dst = &xt[((size_t)ny * 64 + x_l) * 256 + ci0 + oc];
#pragma unroll
    for (int k = 0; k < 8; ++k) dst[k] = tile[oc + k][x_l];
}

__device__ __constant__ float BW[4] = {0.125f, 0.375f, 0.375f, 0.125f};

// ---------------------------------------------------------------------------
// blur of act1 (NHWC 64x64, 8 images) pad(2,2) -> blur1 (NHWC 65x65), fp32
// ---------------------------------------------------------------------------
__global__ void blur1_kernel(const float* __restrict__ act1, float* __restrict__ blur1) {
    int idx = blockIdx.x * 256 + threadIdx.x;     // 8*65*65*64
    int q = (idx & 63) * 4;
    int rem = idx >> 6;
    int xq = rem % 65; rem /= 65;
    int yq = rem % 65;
    int n  = rem / 65;
    float4 acc = {0.f, 0.f, 0.f, 0.f};
#pragma unroll
    for (int i = 0; i < 4; ++i) {
        int yy = yq + i - 2;
        if ((unsigned)yy >= 64u) continue;
#pragma unroll
        for (int j = 0; j < 4; ++j) {
            int xx = xq + j - 2;
            if ((unsigned)xx >= 64u) continue;
            float w = BW[i] * BW[j];
            float4 v = *(const float4*)&act1[((size_t)((n * 64 + yy) * 64 + xx) << 8) + q];
            acc.x += w * v.x; acc.y += w * v.y; acc.z += w * v.z; acc.w += w * v.w;
        }
    }
    *(float4*)&blur1[(size_t)idx * 4] = acc;
}

// ---------------------------------------------------------------------------
// skip blur of xt pad(1,1) sampled at even pos -> skipin [8,32,32,256] fp32
// ---------------------------------------------------------------------------
__global__ void blursample_kernel(const float* __restrict__ xt, float* __restrict__ skipin) {
    int idx = blockIdx.x * 256 + threadIdx.x;     // 8*32*32*64
    int q = (idx & 63) * 4;
    int rem = idx >> 6;
    int xo = rem & 31;
    int yo = (rem >> 5) & 31;
    int n  = rem >> 10;
    float4 acc = {0.f, 0.f, 0.f, 0.f};
#pragma unroll
    for (int i = 0; i < 4; ++i) {
        int yy = 2 * yo + i - 1;
        if ((unsigned)yy >= 64u) continue;
#pragma unroll
        for (int j = 0; j < 4; ++j) {
            int xx = 2 * xo + j - 1;
            if ((unsigned)xx >= 64u) continue;
            float w = BW[i] * BW[j];
            float4 v = *(const float4*)&xt[((size_t)((n * 64 + yy) * 64 + xx) << 8) + q];
            acc.x += w * v.x; acc.y += w * v.y; acc.z += w * v.z; acc.w += w * v.w;
        }
    }
    *(float4*)&skipin[(size_t)idx * 4] = acc;
}

// ---------------------------------------------------------------------------
// conv kernels: implicit GEMM, block tile 128(co)x128(sp), BK=32, split-bf16
// (3 MFMAs: ah*bh + ah*bl + al*bh, fp32 acc). LDS pad 32->40 (16B-aligned rows).
// ---------------------------------------------------------------------------
#define LDK 40

__global__ __launch_bounds__(256, 2) void conv1_kernel(
        const float* __restrict__ xt, const u16* __restrict__ w1h, const u16* __restrict__ w1l,
        const float* __restrict__ b1f, float* __restrict__ act1) {
    __shared__ u16 Ah[128 * LDK];
    __shared__ u16 Al[128 * LDK];
    __shared__ u16 Bh[128 * LDK];
    __shared__ u16 Bl[128 * LDK];
    int tid = threadIdx.x, lane = tid & 63, wid = tid >> 6;
    int col = lane & 15, quad = lane >> 4;
    int wco = (wid >> 1) * 64, wsp = (wid & 1) * 64;
    int sp_base = blockIdx.x * 128;          // over 8*4096
    int co_base = blockIdx.y * 128;
    int n  = sp_base >> 12;
    int y0 = (sp_base & 4095) >> 6;
    int r_st = tid >> 1, k_st = (tid & 1) * 16;

    f32x4 acc[4][4];
#pragma unroll
    for (int i = 0; i < 4; ++i)
#pragma unroll
        for (int j = 0; j < 4; ++j) acc[i][j] = (f32x4){0.f, 0.f, 0.f, 0.f};

    for (int p = 0; p < 9; ++p) {
        int dy = p / 3 - 1, dx = p % 3 - 1;
        const u16* wh = w1h + (size_t)p * 65536;
        const u16* wl = w1l + (size_t)p * 65536;
        for (int kc = 0; kc < 8; ++kc) {
            int ci0 = kc * 32;
            __syncthreads();
            // stage A (pre-split planes): 128x32, 16 u16 per thread per plane
            {
                size_t gs = (size_t)(co_base + r_st) * 256 + ci0 + k_st;
                *(ushort8*)&Ah[r_st * LDK + k_st]     = *(const ushort8*)&wh[gs];
                *(ushort8*)&Ah[r_st * LDK + k_st + 8] = *(const ushort8*)&wh[gs + 8];
                *(ushort8*)&Al[r_st * LDK + k_st]     = *(const ushort8*)&wl[gs];
                *(ushort8*)&Al[r_st * LDK + k_st + 8] = *(const ushort8*)&wl[gs + 8];
            }
            // stage B: read fp32, split in-register
            {
                int yy = y0 + (r_st >> 6) + dy;
                int xx = (r_st & 63) + dx;
                float v[16];
                if ((unsigned)yy < 64u && (unsigned)xx < 64u) {
                    const float* src = &xt[((size_t)((n * 64 + yy) * 64 + xx) << 8) + ci0 + k_st];
#pragma unroll
                    for (int j = 0; j < 16; j += 4) *(float4*)&v[j] = *(const float4*)&src[j];
                } else {
#pragma unroll
                    for (int j = 0; j < 16; ++j) v[j] = 0.f;
                }
                ushort8 h0, h1, l0, l1;
#pragma unroll
                for (int j = 0; j < 8; ++j) { u16 h, l; split2(v[j], h, l); h0[j] = h; l0[j] = l; }
#pragma unroll
                for (int j = 0; j < 8; ++j) { u16 h, l; split2(v[8 + j], h, l); h1[j] = h; l1[j] = l; }
                *(ushort8*)&Bh[r_st * LDK + k_st]     = h0;
                *(ushort8*)&Bh[r_st * LDK + k_st + 8] = h1;
                *(ushort8*)&Bl[r_st * LDK + k_st]     = l0;
                *(ushort8*)&Bl[r_st * LDK + k_st + 8] = l1;
            }
            __syncthreads();
            short8 ah[4], al[4];
#pragma unroll
            for (int tm = 0; tm < 4; ++tm) {
                ah[tm] = *(const short8*)&Ah[(wco + tm * 16 + col) * LDK + quad * 8];
                al[tm] = *(const short8*)&Al[(wco + tm * 16 + col) * LDK + quad * 8];
            }
#pragma unroll
            for (int tn = 0; tn < 4; ++tn) {
                short8 bh = *(const short8*)&Bh[(wsp + tn * 16 + col) * LDK + quad * 8];
                short8 bl = *(const short8*)&Bl[(wsp + tn * 16 + col) * LDK + quad * 8];
#pragma unroll
                for (int tm = 0; tm < 4; ++tm) {
                    acc[tm][tn] = __builtin_amdgcn_mfma_f32_16x16x32_bf16(ah[tm], bh, acc[tm][tn], 0, 0, 0);
                    acc[tm][tn] = __builtin_amdgcn_mfma_f32_16x16x32_bf16(ah[tm], bl, acc[tm][tn], 0, 0, 0);
                    acc[tm][tn] = __builtin_amdgcn_mfma_f32_16x16x32_bf16(al[tm], bh, acc[tm][tn], 0, 0, 0);
                }
            }
        }
    }
    // epilogue: bias + LeakyReLU -> act1 fp32 NHWC (float4 over 4 consecutive co)
#pragma unroll
    for (int tm = 0; tm < 4; ++tm) {
        int co = wco + tm * 16 + quad * 4;       // co_base==0..128; rows here
        int cog = co_base + co;
        float4 bias = *(const float4*)&b1f[cog];
#pragma unroll
        for (int tn = 0; tn < 4; ++tn) {
            int sp = sp_base + wsp + tn * 16 + col;
            float4 o;
            float v0 = acc[tm][tn][0] + bias.x; o.x = v0 > 0.f ? v0 : 0.2f * v0;
            float v1 = acc[tm][tn][1] + bias.y; o.y = v1 > 0.f ? v1 : 0.2f * v1;
            float v2 = acc[tm][tn][2] + bias.z; o.z = v2 > 0.f ? v2 : 0.2f * v2;
            float v3 = acc[tm][tn][3] + bias.w; o.w = v3 > 0.f ? v3 : 0.2f * v3;
            *(float4*)&act1[((size_t)sp << 8) + cog] = o;
        }
    }
}

__global__ __launch_bounds__(256, 2) void conv2_kernel(
        const float* __restrict__ blur1, const float* __restrict__ skipin,
        const u16* __restrict__ w2h, const u16* __restrict__ w2l,
        const u16* __restrict__ wsh, const u16* __restrict__ wsl,
        const float* __restrict__ b2f_, const int* __restrict__ flagp,
        void* __restrict__ out, int n0) {
    __shared__ u16 Ah[128 * LDK];
    __shared__ u16 Al[128 * LDK];
    __shared__ u16 Bh[128 * LDK];
    __shared__ u16 Bl[128 * LDK];
    int tid = threadIdx.x, lane = tid & 63, wid = tid >> 6;
    int col = lane & 15, quad = lane >> 4;
    int wco = (wid >> 1) * 64, wsp = (wid & 1) * 64;
    int sp_base = blockIdx.x * 128;          // over 8*1024
    int co_base = blockIdx.y * 128;
    int n   = sp_base >> 10;
    int yo0 = (sp_base & 1023) >> 5;
    int r_st = tid >> 1, k_st = (tid & 1) * 16;

    f32x4 acc[4][4], accs[4][4];
#pragma unroll
    for (int i = 0; i < 4; ++i)
#pragma unroll
        for (int j = 0; j < 4; ++j) {
            acc[i][j]  = (f32x4){0.f, 0.f, 0.f, 0.f};
            accs[i][j] = (f32x4){0.f, 0.f, 0.f, 0.f};
        }

    // main 3x3 stride-2 conv over blur1 (65x65)
    for (int p = 0; p < 9; ++p) {
        int ky = p / 3, kx = p % 3;
        const u16* wh = w2h + (size_t)p * 131072;
        const u16* wl = w2l + (size_t)p * 131072;
        for (int kc = 0; kc < 8; ++kc) {
            int ci0 = kc * 32;
            __syncthreads();
            {
                size_t gs = (size_t)(co_base + r_st) * 256 + ci0 + k_st;
                *(ushort8*)&Ah[r_st * LDK + k_st]     = *(const ushort8*)&wh[gs];
                *(ushort8*)&Ah[r_st * LDK + k_st + 8] = *(const ushort8*)&wh[gs + 8];
                *(ushort8*)&Al[r_st * LDK + k_st]     = *(const ushort8*)&wl[gs];
                *(ushort8*)&Al[r_st * LDK + k_st + 8] = *(const ushort8*)&wl[gs + 8];
            }
            {
                int yi = 2 * (yo0 + (r_st >> 5)) + ky;   // <= 64 < 65, always valid
                int xi = 2 * (r_st & 31) + kx;
                const float* src = &blur1[(size_t)((n * 65 + yi) * 65 + xi) * 256 + ci0 + k_st];
                float v[16];
#pragma unroll
                for (int j = 0; j < 16; j += 4) *(float4*)&v[j] = *(const float4*)&src[j];
                ushort8 h0, h1, l0, l1;
#pragma unroll
                for (int j = 0; j < 8; ++j) { u16 h, l; split2(v[j], h, l); h0[j] = h; l0[j] = l; }
#pragma unroll
                for (int j = 0; j < 8; ++j) { u16 h, l; split2(v[8 + j], h, l); h1[j] = h; l1[j] = l; }
                *(ushort8*)&Bh[r_st * LDK + k_st]     = h0;
                *(ushort8*)&Bh[r_st * LDK + k_st + 8] = h1;
                *(ushort8*)&Bl[r_st * LDK + k_st]     = l0;
                *(ushort8*)&Bl[r_st * LDK + k_st + 8] = l1;
            }
            __syncthreads();
            short8 ah[4], al[4];
#pragma unroll
            for (int tm = 0; tm < 4; ++tm) {
                ah[tm] = *(const short8*)&Ah[(wco + tm * 16 + col) * LDK + quad * 8];
                al[tm] = *(const short8*)&Al[(wco + tm * 16 + col) * LDK + quad * 8];
            }
#pragma unroll
            for (int tn = 0; tn < 4; ++tn) {
                short8 bh = *(const short8*)&Bh[(wsp + tn * 16 + col) * LDK + quad * 8];
                short8 bl = *(const short8*)&Bl[(wsp + tn * 16 + col) * LDK + quad * 8];
#pragma unroll
                for (int tm = 0; tm < 4; ++tm) {
                    acc[tm][tn] = __builtin_amdgcn_mfma_f32_16x16x32_bf16(ah[tm], bh, acc[tm][tn], 0, 0, 0);
                    acc[tm][tn] = __builtin_amdgcn_mfma_f32_16x16x32_bf16(ah[tm], bl, acc[tm][tn], 0, 0, 0);
                    acc[tm][tn] = __builtin_amdgcn_mfma_f32_16x16x32_bf16(al[tm], bh, acc[tm][tn], 0, 0, 0);
                }
            }
        }
    }
    // skip 1x1 GEMM over skipin
    for (int kc = 0; kc < 8; ++kc) {
        int ci0 = kc * 32;
        __syncthreads();
        {
            size_t gs = (size_t)(co_base + r_st) * 256 + ci0 + k_st;
            *(ushort8*)&Ah[r_st * LDK + k_st]     = *(const ushort8*)&wsh[gs];
            *(ushort8*)&Ah[r_st * LDK + k_st + 8] = *(const ushort8*)&wsh[gs + 8];
            *(ushort8*)&Al[r_st * LDK + k_st]     = *(const ushort8*)&wsl[gs];
            *(ushort8*)&Al[r_st * LDK + k_st + 8] = *(const ushort8*)&wsl[gs + 8];
        }
        {
            const float* src = &skipin[((size_t)(sp_base + r_st) << 8) + ci0 + k_st];
            float v[16];
#pragma unroll
            for (int j = 0; j < 16; j += 4) *(float4*)&v[j] = *(const float4*)&src[j];
            ushort8 h0, h1, l0, l1;
#pragma unroll
            for (int j = 0; j < 8; ++j) { u16 h, l; split2(v[j], h, l); h0[j] = h; l0[j] = l; }
#pragma unroll
            for (int j = 0; j < 8; ++j) { u16 h, l; split2(v[8 + j], h, l); h1[j] = h; l1[j] = l; }
            *(ushort8*)&Bh[r_st * LDK + k_st]     = h0;
            *(ushort8*)&Bh[r_st * LDK + k_st + 8] = h1;
            *(ushort8*)&Bl[r_st * LDK + k_st]     = l0;
            *(ushort8*)&Bl[r_st * LDK + k_st + 8] = l1;
        }
        __syncthreads();
        short8 ah[4], al[4];
#pragma unroll
        for (int tm = 0; tm < 4; ++tm) {
            ah[tm] = *(const short8*)&Ah[(wco + tm * 16 + col) * LDK + quad * 8];
            al[tm] = *(const short8*)&Al[(wco + tm * 16 + col) * LDK + quad * 8];
        }
#pragma unroll
        for (int tn = 0; tn < 4; ++tn) {
            short8 bh = *(const short8*)&Bh[(wsp + tn * 16 + col) * LDK + quad * 8];
            short8 bl = *(const short8*)&Bl[(wsp + tn * 16 + col) * LDK + quad * 8];
#pragma unroll
            for (int tm = 0; tm < 4; ++tm) {
                accs[tm][tn] = __builtin_amdgcn_mfma_f32_16x16x32_bf16(ah[tm], bh, accs[tm][tn], 0, 0, 0);
                accs[tm][tn] = __builtin_amdgcn_mfma_f32_16x16x32_bf16(ah[tm], bl, accs[tm][tn], 0, 0, 0);
                accs[tm][tn] = __builtin_amdgcn_mfma_f32_16x16x32_bf16(al[tm], bh, accs[tm][tn], 0, 0, 0);
            }
        }
    }
    // epilogue -> out NCHW (dtype per flag)
    const float RS2 = 0.70710678118654752f;
    int flag = flagp[0];
#pragma unroll
    for (int tm = 0; tm < 4; ++tm) {
        int cog = co_base + wco + tm * 16 + quad * 4;
        float4 bias = *(const float4*)&b2f_[cog];
        float bb[4] = {bias.x, bias.y, bias.z, bias.w};
#pragma unroll
        for (int tn = 0; tn < 4; ++tn) {
            int sp  = sp_base + wsp + tn * 16 + col;
            int ng  = n0 + (sp >> 10);
            int rem = sp & 1023;
            size_t ob = ((size_t)ng * 512 + cog) * 1024 + rem;
#pragma unroll
            for (int r = 0; r < 4; ++r) {
                float v = acc[tm][tn][r] + bb[r];
                v = v > 0.f ? v : 0.2f * v;
                v = (v + accs[tm][tn][r]) * RS2;
                if (flag) ((float*)out)[ob + (size_t)r * 1024] = v;
                else      ((u16*)out)[ob + (size_t)r * 1024]   = f2b(v);
            }
        }
    }
}

// ---------------------------------------------------------------------------
// Workspace (bytes), peak ~84.2 MB, chunked over 2x8 images:
//   0         flag(4)
//   64        inv_sigma(12)
//   1024      b1f (1KB)  2048 b2f (2KB)
//   4096      w1h 1179648 | 1183744 w1l | 2363392 w2h 2359296 | 4722688 w2l
//   7081984   wsh 262144  | 7344128 wsl
//   7606272   xt/blur1 region (max 34611200)
//   42217472  act1 33554432
//   75771904  skipin 8388608   -> end 84160512
// ---------------------------------------------------------------------------
extern "C" void kernel_launch(void* const* d_in, const int* in_sizes, int n_in,
                              void* d_out, int out_size, void* d_ws, size_t ws_size,
                              hipStream_t stream) {
    const void* x   = d_in[0];
    const void* w1b = d_in[1];
    const void* u1  = d_in[2];
    const void* b1  = d_in[4];
    const void* w2b = d_in[5];
    const void* u2  = d_in[6];
    const void* b2  = d_in[8];
    const void* wsb = d_in[9];
    const void* us  = d_in[10];

    char* ws = (char*)d_ws;
    int*   flag      = (int*)(ws);
    float* inv_sigma = (float*)(ws + 64);
    float* b1f       = (float*)(ws + 1024);
    float* b2fp      = (float*)(ws + 2048);
    u16* w1h = (u16*)(ws + 4096);
    u16* w1l = (u16*)(ws + 1183744);
    u16* w2h = (u16*)(ws + 2363392);
    u16* w2l = (u16*)(ws + 4722688);
    u16* wsh = (u16*)(ws + 7081984);
    u16* wsl = (u16*)(ws + 7344128);
    float* xt     = (float*)(ws + 7606272);
    float* blur1  = xt;                       // aliased: xt dead after conv1
    float* act1   = (float*)(ws + 42217472);
    float* skipin = (float*)(ws + 75771904);

    detect_kernel<<<1, 256, 0, stream>>>((const unsigned*)x, flag);
    sigma_kernel<<<3, 256, 0, stream>>>(w1b, u1, w2b, u2, wsb, us, flag, inv_sigma);
    wprep_kernel<<<7427, 256, 0, stream>>>(w1b, w2b, wsb, b1, b2, inv_sigma, flag,
                                           w1h, w1l, w2h, w2l, wsh, wsl, b1f, b2fp);
    for (int c = 0; c < 2; ++c) {
        int n0 = c * 8;
        transpose_kernel<<<dim3(512, 8), 256, 0, stream>>>(x, xt, flag, n0);
        blursample_kernel<<<2048, 256, 0, stream>>>(xt, skipin);
        conv1_kernel<<<dim3(256, 2), 256, 0, stream>>>(xt, w1h, w1l, b1f, act1);
        blur1_kernel<<<8450, 256, 0, stream>>>(act1, blur1);
        conv2_kernel<<<dim3(64, 4), 256, 0, stream>>>(blur1, skipin, w2h, w2l, wsh, wsl,
                                                      b2fp, flag, d_out, n0);
    }
}

// Round 3
// 844.096 us; speedup vs baseline: 2.0938x; 2.0938x over previous
//
#include <hip/hip_runtime.h>
#include <math.h>

typedef unsigned short u16;
typedef __attribute__((ext_vector_type(8))) unsigned short ushort8;
typedef __attribute__((ext_vector_type(8))) short short8;
typedef __attribute__((ext_vector_type(4))) float f32x4;

__device__ __forceinline__ float b2f(u16 v) {
    unsigned u = ((unsigned)v) << 16; float f; __builtin_memcpy(&f, &u, 4); return f;
}
__device__ __forceinline__ u16 f2b(float f) {
    unsigned u; __builtin_memcpy(&u, &f, 4);
    u = (u + 0x7fffu + ((u >> 16) & 1u)) >> 16;   // RNE
    return (u16)u;
}
// flag-branched raw-input load (flag: 1 = fp32 inputs, 0 = bf16 inputs)
__device__ __forceinline__ float ldin(const void* p, int i, int flag) {
    return flag ? ((const float*)p)[i] : b2f(((const u16*)p)[i]);
}
__device__ __forceinline__ void split2(float x, u16& h, u16& l) {
    h = f2b(x);
    l = f2b(x - b2f(h));
}

// ---------------------------------------------------------------------------
// dtype detector: fp32 N(0,1) words have exponent field in [77,157];
// bf16 pairs viewed as fp32 essentially never do. flag=1 -> fp32.
// ---------------------------------------------------------------------------
__global__ void detect_kernel(const unsigned* __restrict__ xw, int* __restrict__ flag) {
    __shared__ int red[4];
    int tid = threadIdx.x, lane = tid & 63, wid = tid >> 6;
    int cnt = 0;
    for (int i = 0; i < 16; ++i) {
        unsigned w = xw[tid * 16 + i];
        unsigned e = (w >> 23) & 0xFF;
        if (e >= 77u && e <= 157u) ++cnt;
    }
    for (int o = 32; o; o >>= 1) cnt += __shfl_down(cnt, o, 64);
    if (lane == 0) red[wid] = cnt;
    __syncthreads();
    if (tid == 0) flag[0] = (red[0] + red[1] + red[2] + red[3] >= 2048) ? 1 : 0;
}

// ---------------------------------------------------------------------------
// Parallel spectral norm. t layout: [0]=t1(2304) [2304]=t2(2304) [4608]=ts(256)
// ---------------------------------------------------------------------------
__global__ void sig_init_kernel(float* __restrict__ t, float* __restrict__ ns) {
    int i = blockIdx.x * 256 + threadIdx.x;
    if (i < 4864) t[i] = 0.f;
    if (i < 3) ns[i] = 0.f;
}

// t = W^T u, grid-parallel over (weight, j-chunk of 256, i-chunk of 64)
__global__ void sig_t_kernel(const void* __restrict__ w1, const void* __restrict__ u1,
                             const void* __restrict__ w2, const void* __restrict__ u2,
                             const void* __restrict__ wsb, const void* __restrict__ us,
                             const int* __restrict__ flagp, float* __restrict__ t) {
    __shared__ float ush[64];
    int blk = blockIdx.x;
    int flag = flagp[0];
    const void* W; const void* U; int m, toff, jc, ic;
    if (blk < 36)       { W = w1;  U = u1; m = 2304; toff = 0;    jc = blk % 9; ic = blk / 9; }
    else if (blk < 108) { int r = blk - 36;  W = w2;  U = u2; m = 2304; toff = 2304; jc = r % 9; ic = r / 9; }
    else                { int r = blk - 108; W = wsb; U = us; m = 256;  toff = 4608; jc = 0;     ic = r; }
    int tid = threadIdx.x;
    if (tid < 64) ush[tid] = ldin(U, ic * 64 + tid, flag);
    __syncthreads();
    int j = jc * 256 + tid;
    float acc = 0.f;
    int base = ic * 64 * m + j;
    for (int ii = 0; ii < 64; ++ii) acc += ldin(W, base + ii * m, flag) * ush[ii];
    atomicAdd(&t[toff + j], acc);
}

__global__ void sig_norm_kernel(float* __restrict__ t, float* __restrict__ ntinv) {
    __shared__ float red[4];
    int b = blockIdx.x;
    int m = (b == 2) ? 256 : 2304;
    int toff = b * 2304;
    int tid = threadIdx.x, lane = tid & 63, wid = tid >> 6;
    float s = 0.f;
    for (int j = tid; j < m; j += 256) { float v = t[toff + j]; s += v * v; }
    for (int o = 32; o; o >>= 1) s += __shfl_down(s, o, 64);
    if (lane == 0) red[wid] = s;
    __syncthreads();
    if (tid == 0) ntinv[b] = 1.f / (sqrtf(red[0] + red[1] + red[2] + red[3]) + 1e-12f);
}

// s_i = (W t)_i * ntinv ; ns_b += s_i^2. One wave per row.
__global__ void sig_s_kernel(const void* __restrict__ w1, const void* __restrict__ w2,
                             const void* __restrict__ wsb, const int* __restrict__ flagp,
                             const float* __restrict__ t, const float* __restrict__ ntinv,
                             float* __restrict__ ns) {
    int flag = flagp[0];
    int wg = blockIdx.x * 4 + (threadIdx.x >> 6);   // 0..1279
    int lane = threadIdx.x & 63;
    const void* W; int m, toff, i, b;
    if (wg < 256)      { W = w1;  m = 2304; toff = 0;    i = wg;       b = 0; }
    else if (wg < 768) { W = w2;  m = 2304; toff = 2304; i = wg - 256; b = 1; }
    else               { W = wsb; m = 256;  toff = 4608; i = wg - 768; b = 2; }
    float acc = 0.f;
    int base = i * m;
    for (int j = lane; j < m; j += 64) acc += ldin(W, base + j, flag) * t[toff + j];
    for (int o = 32; o; o >>= 1) acc += __shfl_down(acc, o, 64);
    if (lane == 0) { float s = acc * ntinv[b]; atomicAdd(&ns[b], s * s); }
}

__global__ void sig_fin_kernel(const float* __restrict__ ns, float* __restrict__ inv_sigma) {
    int b = threadIdx.x;
    if (b < 3) { float s2 = ns[b]; float s = sqrtf(s2); inv_sigma[b] = (s + 1e-12f) / s2; }
}

// ---------------------------------------------------------------------------
// Weight prep: scale by 1/sigma, transpose to [kyx][co][ci], split hi/lo.
// Also canonicalizes biases to fp32.
// ---------------------------------------------------------------------------
__global__ void wprep_kernel(const void* __restrict__ w1b, const void* __restrict__ w2b,
                             const void* __restrict__ wsb,
                             const void* __restrict__ b1,  const void* __restrict__ b2,
                             const float* __restrict__ inv_sigma, const int* __restrict__ flagp,
                             u16* __restrict__ w1h, u16* __restrict__ w1l,
                             u16* __restrict__ w2h, u16* __restrict__ w2l,
                             u16* __restrict__ wsh, u16* __restrict__ wsl,
                             float* __restrict__ b1f, float* __restrict__ b2f_) {
    int idx = blockIdx.x * 256 + threadIdx.x;
    int flag = flagp[0];
    float s0 = inv_sigma[0], s1 = inv_sigma[1], s2 = inv_sigma[2];
    if (idx < 589824) {                       // 9*256*256
        int kyx = idx / 65536; int rem = idx - kyx * 65536;
        int co = rem >> 8, ci = rem & 255;
        float w = ldin(w1b, ((co << 8) + ci) * 9 + kyx, flag) * s0;
        split2(w, w1h[idx], w1l[idx]);
    } else if (idx < 589824 + 1179648) {      // 9*512*256
        int i2 = idx - 589824;
        int kyx = i2 / 131072; int rem = i2 - kyx * 131072;
        int co = rem >> 8, ci = rem & 255;
        float w = ldin(w2b, ((co << 8) + ci) * 9 + kyx, flag) * s1;
        split2(w, w2h[i2], w2l[i2]);
    } else if (idx < 1900544) {               // 512*256
        int i3 = idx - 1769472;
        float w = ldin(wsb, i3, flag) * s2;
        split2(w, wsh[i3], wsl[i3]);
    } else if (idx < 1900544 + 256) {
        b1f[idx - 1900544] = ldin(b1, idx - 1900544, flag);
    } else if (idx < 1900544 + 768) {
        b2f_[idx - 1900800] = ldin(b2, idx - 1900800, flag);
    }
}

// ---------------------------------------------------------------------------
// x NCHW -> xt fp32 NHWC for one 8-image chunk
// ---------------------------------------------------------------------------
__global__ void transpose_kernel(const void* __restrict__ x, float* __restrict__ xt,
                                 const int* __restrict__ flagp, int n0) {
    __shared__ float tile[32][65];
    int flag = flagp[0];
    int ny  = blockIdx.x;                    // nl*64 + y
    int ci0 = blockIdx.y * 32;
    int nl = ny >> 6, y = ny & 63;
    int t = threadIdx.x;
    int ci_l = t >> 3, x8 = (t & 7) * 8;
    int base = ((n0 + nl) * 256 + ci0 + ci_l) * 4096 + y * 64 + x8;
#pragma unroll
    for (int k = 0; k < 8; ++k) tile[ci_l][x8 + k] = ldin(x, base + k, flag);
    __syncthreads();
    int x_l = t >> 2, oc = (t & 3) * 8;
    float* dst = &xt[((size_t)ny * 64 + x_l) * 256 + ci0 + oc];
#pragma unroll
    for (int k = 0; k < 8; ++k) dst[k] = tile[oc + k][x_l];
}

__device__ __constant__ float BW[4] = {0.125f, 0.375f, 0.375f, 0.125f};

// ---------------------------------------------------------------------------
// blur of act1 (NHWC 64x64, 8 images) pad(2,2) -> blur1 (NHWC 65x65), fp32
// ---------------------------------------------------------------------------
__global__ void blur1_kernel(const float* __restrict__ act1, float* __restrict__ blur1) {
    int idx = blockIdx.x * 256 + threadIdx.x;     // 8*65*65*64
    int q = (idx & 63) * 4;
    int rem = idx >> 6;
    int xq = rem % 65; rem /= 65;
    int yq = rem % 65;
    int n  = rem / 65;
    float4 acc = {0.f, 0.f, 0.f, 0.f};
#pragma unroll
    for (int i = 0; i < 4; ++i) {
        int yy = yq + i - 2;
        if ((unsigned)yy >= 64u) continue;
#pragma unroll
        for (int j = 0; j < 4; ++j) {
            int xx = xq + j - 2;
            if ((unsigned)xx >= 64u) continue;
            float w = BW[i] * BW[j];
            float4 v = *(const float4*)&act1[((size_t)((n * 64 + yy) * 64 + xx) << 8) + q];
            acc.x += w * v.x; acc.y += w * v.y; acc.z += w * v.z; acc.w += w * v.w;
        }
    }
    *(float4*)&blur1[(size_t)idx * 4] = acc;
}

// ---------------------------------------------------------------------------
// skip blur of xt pad(1,1) sampled at even pos -> skipin [8,32,32,256] fp32
// ---------------------------------------------------------------------------
__global__ void blursample_kernel(const float* __restrict__ xt, float* __restrict__ skipin) {
    int idx = blockIdx.x * 256 + threadIdx.x;     // 8*32*32*64
    int q = (idx & 63) * 4;
    int rem = idx >> 6;
    int xo = rem & 31;
    int yo = (rem >> 5) & 31;
    int n  = rem >> 10;
    float4 acc = {0.f, 0.f, 0.f, 0.f};
#pragma unroll
    for (int i = 0; i < 4; ++i) {
        int yy = 2 * yo + i - 1;
        if ((unsigned)yy >= 64u) continue;
#pragma unroll
        for (int j = 0; j < 4; ++j) {
            int xx = 2 * xo + j - 1;
            if ((unsigned)xx >= 64u) continue;
            float w = BW[i] * BW[j];
            float4 v = *(const float4*)&xt[((size_t)((n * 64 + yy) * 64 + xx) << 8) + q];
            acc.x += w * v.x; acc.y += w * v.y; acc.z += w * v.z; acc.w += w * v.w;
        }
    }
    *(float4*)&skipin[(size_t)idx * 4] = acc;
}

// ---------------------------------------------------------------------------
// conv kernels: implicit GEMM, block tile 128(co)x128(sp), BK=32.
// DOLO=1: split-bf16 (3 MFMAs, fp32-grade accuracy). DOLO=0: plain bf16 hi.
// ---------------------------------------------------------------------------
#define LDK 40

template <bool DOLO>
__device__ __forceinline__ void conv1_body(
        const float* __restrict__ xt, const u16* __restrict__ w1h, const u16* __restrict__ w1l,
        const float* __restrict__ b1f, float* __restrict__ act1,
        u16* Ah, u16* Al, u16* Bh, u16* Bl) {
    int tid = threadIdx.x, lane = tid & 63, wid = tid >> 6;
    int col = lane & 15, quad = lane >> 4;
    int wco = (wid >> 1) * 64, wsp = (wid & 1) * 64;
    int sp_base = blockIdx.x * 128;          // over 8*4096
    int co_base = blockIdx.y * 128;
    int n  = sp_base >> 12;
    int y0 = (sp_base & 4095) >> 6;
    int r_st = tid >> 1, k_st = (tid & 1) * 16;

    f32x4 acc[4][4];
#pragma unroll
    for (int i = 0; i < 4; ++i)
#pragma unroll
        for (int j = 0; j < 4; ++j) acc[i][j] = (f32x4){0.f, 0.f, 0.f, 0.f};

    for (int p = 0; p < 9; ++p) {
        int dy = p / 3 - 1, dx = p % 3 - 1;
        const u16* wh = w1h + (size_t)p * 65536;
        const u16* wl = w1l + (size_t)p * 65536;
        for (int kc = 0; kc < 8; ++kc) {
            int ci0 = kc * 32;
            __syncthreads();
            {
                size_t gs = (size_t)(co_base + r_st) * 256 + ci0 + k_st;
                *(ushort8*)&Ah[r_st * LDK + k_st]     = *(const ushort8*)&wh[gs];
                *(ushort8*)&Ah[r_st * LDK + k_st + 8] = *(const ushort8*)&wh[gs + 8];
                if (DOLO) {
                    *(ushort8*)&Al[r_st * LDK + k_st]     = *(const ushort8*)&wl[gs];
                    *(ushort8*)&Al[r_st * LDK + k_st + 8] = *(const ushort8*)&wl[gs + 8];
                }
            }
            {
                int yy = y0 + (r_st >> 6) + dy;
                int xx = (r_st & 63) + dx;
                float v[16];
                if ((unsigned)yy < 64u && (unsigned)xx < 64u) {
                    const float* src = &xt[((size_t)((n * 64 + yy) * 64 + xx) << 8) + ci0 + k_st];
#pragma unroll
                    for (int j = 0; j < 16; j += 4) *(float4*)&v[j] = *(const float4*)&src[j];
                } else {
#pragma unroll
                    for (int j = 0; j < 16; ++j) v[j] = 0.f;
                }
                ushort8 h0, h1, l0, l1;
#pragma unroll
                for (int j = 0; j < 8; ++j) {
                    if (DOLO) { u16 h, l; split2(v[j], h, l); h0[j] = h; l0[j] = l; }
                    else      { h0[j] = f2b(v[j]); }
                }
#pragma unroll
                for (int j = 0; j < 8; ++j) {
                    if (DOLO) { u16 h, l; split2(v[8 + j], h, l); h1[j] = h; l1[j] = l; }
                    else      { h1[j] = f2b(v[8 + j]); }
                }
                *(ushort8*)&Bh[r_st * LDK + k_st]     = h0;
                *(ushort8*)&Bh[r_st * LDK + k_st + 8] = h1;
                if (DOLO) {
                    *(ushort8*)&Bl[r_st * LDK + k_st]     = l0;
                    *(ushort8*)&Bl[r_st * LDK + k_st + 8] = l1;
                }
            }
            __syncthreads();
            short8 ah[4], al[4];
#pragma unroll
            for (int tm = 0; tm < 4; ++tm) {
                ah[tm] = *(const short8*)&Ah[(wco + tm * 16 + col) * LDK + quad * 8];
                if (DOLO) al[tm] = *(const short8*)&Al[(wco + tm * 16 + col) * LDK + quad * 8];
            }
#pragma unroll
            for (int tn = 0; tn < 4; ++tn) {
                short8 bh = *(const short8*)&Bh[(wsp + tn * 16 + col) * LDK + quad * 8];
                short8 bl;
                if (DOLO) bl = *(const short8*)&Bl[(wsp + tn * 16 + col) * LDK + quad * 8];
#pragma unroll
                for (int tm = 0; tm < 4; ++tm) {
                    acc[tm][tn] = __builtin_amdgcn_mfma_f32_16x16x32_bf16(ah[tm], bh, acc[tm][tn], 0, 0, 0);
                    if (DOLO) {
                        acc[tm][tn] = __builtin_amdgcn_mfma_f32_16x16x32_bf16(ah[tm], bl, acc[tm][tn], 0, 0, 0);
                        acc[tm][tn] = __builtin_amdgcn_mfma_f32_16x16x32_bf16(al[tm], bh, acc[tm][tn], 0, 0, 0);
                    }
                }
            }
        }
    }
#pragma unroll
    for (int tm = 0; tm < 4; ++tm) {
        int cog = co_base + (wid >> 1) * 64 + tm * 16 + quad * 4;
        float4 bias = *(const float4*)&b1f[cog];
#pragma unroll
        for (int tn = 0; tn < 4; ++tn) {
            int sp = sp_base + wsp + tn * 16 + col;
            float4 o;
            float v0 = acc[tm][tn][0] + bias.x; o.x = v0 > 0.f ? v0 : 0.2f * v0;
            float v1 = acc[tm][tn][1] + bias.y; o.y = v1 > 0.f ? v1 : 0.2f * v1;
            float v2 = acc[tm][tn][2] + bias.z; o.z = v2 > 0.f ? v2 : 0.2f * v2;
            float v3 = acc[tm][tn][3] + bias.w; o.w = v3 > 0.f ? v3 : 0.2f * v3;
            *(float4*)&act1[((size_t)sp << 8) + cog] = o;
        }
    }
}

__global__ __launch_bounds__(256, 2) void conv1_kernel(
        const float* __restrict__ xt, const u16* __restrict__ w1h, const u16* __restrict__ w1l,
        const float* __restrict__ b1f, float* __restrict__ act1, const int* __restrict__ flagp) {
    __shared__ u16 Ah[128 * LDK];
    __shared__ u16 Al[128 * LDK];
    __shared__ u16 Bh[128 * LDK];
    __shared__ u16 Bl[128 * LDK];
    if (flagp[0]) conv1_body<true >(xt, w1h, w1l, b1f, act1, Ah, Al, Bh, Bl);
    else          conv1_body<false>(xt, w1h, w1l, b1f, act1, Ah, Al, Bh, Bl);
}

template <bool DOLO>
__device__ __forceinline__ void conv2_body(
        const float* __restrict__ blur1, const float* __restrict__ skipin,
        const u16* __restrict__ w2h, const u16* __restrict__ w2l,
        const u16* __restrict__ wsh, const u16* __restrict__ wsl,
        const float* __restrict__ b2f_, void* __restrict__ out, int n0,
        u16* Ah, u16* Al, u16* Bh, u16* Bl, int flag) {
    int tid = threadIdx.x, lane = tid & 63, wid = tid >> 6;
    int col = lane & 15, quad = lane >> 4;
    int wco = (wid >> 1) * 64, wsp = (wid & 1) * 64;
    int sp_base = blockIdx.x * 128;          // over 8*1024
    int co_base = blockIdx.y * 128;
    int n   = sp_base >> 10;
    int yo0 = (sp_base & 1023) >> 5;
    int r_st = tid >> 1, k_st = (tid & 1) * 16;

    f32x4 acc[4][4], accs[4][4];
#pragma unroll
    for (int i = 0; i < 4; ++i)
#pragma unroll
        for (int j = 0; j < 4; ++j) {
            acc[i][j]  = (f32x4){0.f, 0.f, 0.f, 0.f};
            accs[i][j] = (f32x4){0.f, 0.f, 0.f, 0.f};
        }

    // 3x3 stride-2 conv over blur1 (65x65), then skip 1x1 GEMM as pass p=9
    for (int p = 0; p < 10; ++p) {
        int ky = p / 3, kx = p % 3;
        const u16* wh = (p < 9) ? w2h + (size_t)p * 131072 : wsh;
        const u16* wl = (p < 9) ? w2l + (size_t)p * 131072 : wsl;
        for (int kc = 0; kc < 8; ++kc) {
            int ci0 = kc * 32;
            __syncthreads();
            {
                size_t gs = (size_t)(co_base + r_st) * 256 + ci0 + k_st;
                *(ushort8*)&Ah[r_st * LDK + k_st]     = *(const ushort8*)&wh[gs];
                *(ushort8*)&Ah[r_st * LDK + k_st + 8] = *(const ushort8*)&wh[gs + 8];
                if (DOLO) {
                    *(ushort8*)&Al[r_st * LDK + k_st]     = *(const ushort8*)&wl[gs];
                    *(ushort8*)&Al[r_st * LDK + k_st + 8] = *(const ushort8*)&wl[gs + 8];
                }
            }
            {
                const float* src;
                if (p < 9) {
                    int yi = 2 * (yo0 + (r_st >> 5)) + ky;
                    int xi = 2 * (r_st & 31) + kx;
                    src = &blur1[(size_t)((n * 65 + yi) * 65 + xi) * 256 + ci0 + k_st];
                } else {
                    src = &skipin[((size_t)(sp_base + r_st) << 8) + ci0 + k_st];
                }
                float v[16];
#pragma unroll
                for (int j = 0; j < 16; j += 4) *(float4*)&v[j] = *(const float4*)&src[j];
                ushort8 h0, h1, l0, l1;
#pragma unroll
                for (int j = 0; j < 8; ++j) {
                    if (DOLO) { u16 h, l; split2(v[j], h, l); h0[j] = h; l0[j] = l; }
                    else      { h0[j] = f2b(v[j]); }
                }
#pragma unroll
                for (int j = 0; j < 8; ++j) {
                    if (DOLO) { u16 h, l; split2(v[8 + j], h, l); h1[j] = h; l1[j] = l; }
                    else      { h1[j] = f2b(v[8 + j]); }
                }
                *(ushort8*)&Bh[r_st * LDK + k_st]     = h0;
                *(ushort8*)&Bh[r_st * LDK + k_st + 8] = h1;
                if (DOLO) {
                    *(ushort8*)&Bl[r_st * LDK + k_st]     = l0;
                    *(ushort8*)&Bl[r_st * LDK + k_st + 8] = l1;
                }
            }
            __syncthreads();
            short8 ah[4], al[4];
#pragma unroll
            for (int tm = 0; tm < 4; ++tm) {
                ah[tm] = *(const short8*)&Ah[(wco + tm * 16 + col) * LDK + quad * 8];
                if (DOLO) al[tm] = *(const short8*)&Al[(wco + tm * 16 + col) * LDK + quad * 8];
            }
            if (p < 9) {
#pragma unroll
                for (int tn = 0; tn < 4; ++tn) {
                    short8 bh = *(const short8*)&Bh[(wsp + tn * 16 + col) * LDK + quad * 8];
                    short8 bl;
                    if (DOLO) bl = *(const short8*)&Bl[(wsp + tn * 16 + col) * LDK + quad * 8];
#pragma unroll
                    for (int tm = 0; tm < 4; ++tm) {
                        acc[tm][tn] = __builtin_amdgcn_mfma_f32_16x16x32_bf16(ah[tm], bh, acc[tm][tn], 0, 0, 0);
                        if (DOLO) {
                            acc[tm][tn] = __builtin_amdgcn_mfma_f32_16x16x32_bf16(ah[tm], bl, acc[tm][tn], 0, 0, 0);
                            acc[tm][tn] = __builtin_amdgcn_mfma_f32_16x16x32_bf16(al[tm], bh, acc[tm][tn], 0, 0, 0);
                        }
                    }
                }
            } else {
#pragma unroll
                for (int tn = 0; tn < 4; ++tn) {
                    short8 bh = *(const short8*)&Bh[(wsp + tn * 16 + col) * LDK + quad * 8];
                    short8 bl;
                    if (DOLO) bl = *(const short8*)&Bl[(wsp + tn * 16 + col) * LDK + quad * 8];
#pragma unroll
                    for (int tm = 0; tm < 4; ++tm) {
                        accs[tm][tn] = __builtin_amdgcn_mfma_f32_16x16x32_bf16(ah[tm], bh, accs[tm][tn], 0, 0, 0);
                        if (DOLO) {
                            accs[tm][tn] = __builtin_amdgcn_mfma_f32_16x16x32_bf16(ah[tm], bl, accs[tm][tn], 0, 0, 0);
                            accs[tm][tn] = __builtin_amdgcn_mfma_f32_16x16x32_bf16(al[tm], bh, accs[tm][tn], 0, 0, 0);
                        }
                    }
                }
            }
        }
    }
    const float RS2 = 0.70710678118654752f;
#pragma unroll
    for (int tm = 0; tm < 4; ++tm) {
        int cog = co_base + wco + tm * 16 + quad * 4;
        float4 bias = *(const float4*)&b2f_[cog];
        float bb[4] = {bias.x, bias.y, bias.z, bias.w};
#pragma unroll
        for (int tn = 0; tn < 4; ++tn) {
            int sp  = sp_base + wsp + tn * 16 + col;
            int ng  = n0 + (sp >> 10);
            int rem = sp & 1023;
            size_t ob = ((size_t)ng * 512 + cog) * 1024 + rem;
#pragma unroll
            for (int r = 0; r < 4; ++r) {
                float v = acc[tm][tn][r] + bb[r];
                v = v > 0.f ? v : 0.2f * v;
                v = (v + accs[tm][tn][r]) * RS2;
                if (flag) ((float*)out)[ob + (size_t)r * 1024] = v;
                else      ((u16*)out)[ob + (size_t)r * 1024]   = f2b(v);
            }
        }
    }
}

__global__ __launch_bounds__(256, 2) void conv2_kernel(
        const float* __restrict__ blur1, const float* __restrict__ skipin,
        const u16* __restrict__ w2h, const u16* __restrict__ w2l,
        const u16* __restrict__ wsh, const u16* __restrict__ wsl,
        const float* __restrict__ b2f_, const int* __restrict__ flagp,
        void* __restrict__ out, int n0) {
    __shared__ u16 Ah[128 * LDK];
    __shared__ u16 Al[128 * LDK];
    __shared__ u16 Bh[128 * LDK];
    __shared__ u16 Bl[128 * LDK];
    int flag = flagp[0];
    if (flag) conv2_body<true >(blur1, skipin, w2h, w2l, wsh, wsl, b2f_, out, n0, Ah, Al, Bh, Bl, flag);
    else      conv2_body<false>(blur1, skipin, w2h, w2l, wsh, wsl, b2f_, out, n0, Ah, Al, Bh, Bl, flag);
}

// ---------------------------------------------------------------------------
// Workspace (bytes), total 84,160,512 (same proven footprint as round 2):
//   0        flag | 64 inv_sigma
//   1024     b1f  | 2048 b2f
//   4096     w1h  | 1183744 w1l | 2363392 w2h | 4722688 w2l | 7081984 wsh | 7344128 wsl
//   7606272  xt/blur1 region (34,611,200); sigma scratch t/ntinv/ns aliased at its head
//   42217472 act1 (33,554,432)
//   75771904 skipin (8,388,608)
// ---------------------------------------------------------------------------
extern "C" void kernel_launch(void* const* d_in, const int* in_sizes, int n_in,
                              void* d_out, int out_size, void* d_ws, size_t ws_size,
                              hipStream_t stream) {
    const void* x   = d_in[0];
    const void* w1b = d_in[1];
    const void* u1  = d_in[2];
    const void* b1  = d_in[4];
    const void* w2b = d_in[5];
    const void* u2  = d_in[6];
    const void* b2  = d_in[8];
    const void* wsb = d_in[9];
    const void* us  = d_in[10];

    char* ws = (char*)d_ws;
    int*   flag      = (int*)(ws);
    float* inv_sigma = (float*)(ws + 64);
    float* b1f       = (float*)(ws + 1024);
    float* b2fp      = (float*)(ws + 2048);
    u16* w1h = (u16*)(ws + 4096);
    u16* w1l = (u16*)(ws + 1183744);
    u16* w2h = (u16*)(ws + 2363392);
    u16* w2l = (u16*)(ws + 4722688);
    u16* wsh = (u16*)(ws + 7081984);
    u16* wsl = (u16*)(ws + 7344128);
    float* xt     = (float*)(ws + 7606272);
    float* blur1  = xt;                       // aliased: xt dead after conv1
    float* act1   = (float*)(ws + 42217472);
    float* skipin = (float*)(ws + 75771904);
    // sigma scratch aliased into the head of the xt region (dead before transpose)
    float* tvec  = (float*)(ws + 7606272);    // 4864 floats
    float* ntinv = (float*)(ws + 7606272 + 19456);
    float* ns    = (float*)(ws + 7606272 + 19520);

    detect_kernel<<<1, 256, 0, stream>>>((const unsigned*)x, flag);
    sig_init_kernel<<<19, 256, 0, stream>>>(tvec, ns);
    sig_t_kernel<<<116, 256, 0, stream>>>(w1b, u1, w2b, u2, wsb, us, flag, tvec);
    sig_norm_kernel<<<3, 256, 0, stream>>>(tvec, ntinv);
    sig_s_kernel<<<320, 256, 0, stream>>>(w1b, w2b, wsb, flag, tvec, ntinv, ns);
    sig_fin_kernel<<<1, 64, 0, stream>>>(ns, inv_sigma);
    wprep_kernel<<<7427, 256, 0, stream>>>(w1b, w2b, wsb, b1, b2, inv_sigma, flag,
                                           w1h, w1l, w2h, w2l, wsh, wsl, b1f, b2fp);
    for (int c = 0; c < 2; ++c) {
        int n0 = c * 8;
        transpose_kernel<<<dim3(512, 8), 256, 0, stream>>>(x, xt, flag, n0);
        blursample_kernel<<<2048, 256, 0, stream>>>(xt, skipin);
        conv1_kernel<<<dim3(256, 2), 256, 0, stream>>>(xt, w1h, w1l, b1f, act1, flag);
        blur1_kernel<<<8450, 256, 0, stream>>>(act1, blur1);
        conv2_kernel<<<dim3(64, 4), 256, 0, stream>>>(blur1, skipin, w2h, w2l, wsh, wsl,
                                                      b2fp, flag, d_out, n0);
    }
}